// Round 4
// baseline (1413.005 us; speedup 1.0000x reference)
//
#include <hip/hip_runtime.h>
#include <hip/hip_fp16.h>

typedef _Float16 half8 __attribute__((ext_vector_type(8)));
typedef float floatx4 __attribute__((ext_vector_type(4)));

#define GLL16(g, l)                                                            \
  __builtin_amdgcn_global_load_lds(                                            \
      (const __attribute__((address_space(1))) void*)(g),                      \
      (__attribute__((address_space(3))) void*)(l), 16, 0, 0)

#define TAU 0.25f

// ---------------------------------------------------------------------------
// Kernel 0a: transpose x [b=16, c=512, s=2048] f32 -> xh [row=b*2048+s][c] f16
// ---------------------------------------------------------------------------
__global__ void tsplit_x(const float* __restrict__ x, _Float16* __restrict__ xh) {
  __shared__ float tile[32][33];
  const int s0 = blockIdx.x * 32;
  const int c0 = blockIdx.y * 32;
  const int b = blockIdx.z;
  const int tx = threadIdx.x, ty = threadIdx.y;
  const float* src = x + ((size_t)b * 512 + c0) * 2048 + s0;
#pragma unroll
  for (int i = ty; i < 32; i += 8) tile[i][tx] = src[(size_t)i * 2048 + tx];
  __syncthreads();
#pragma unroll
  for (int j = ty; j < 32; j += 8) {
    const int row = b * 2048 + s0 + j;
    xh[(size_t)row * 512 + c0 + tx] = (_Float16)tile[tx][j];
  }
}

// ---------------------------------------------------------------------------
// Kernel 0b: transpose centroids [c=512, n=8192] f32 -> cth [n][c] f16
// ---------------------------------------------------------------------------
__global__ void tsplit_c(const float* __restrict__ c, _Float16* __restrict__ cth) {
  __shared__ float tile[32][33];
  const int n0 = blockIdx.x * 32;
  const int c0 = blockIdx.y * 32;
  const int tx = threadIdx.x, ty = threadIdx.y;
#pragma unroll
  for (int i = ty; i < 32; i += 8) tile[i][tx] = c[(size_t)(c0 + i) * 8192 + n0 + tx];
  __syncthreads();
#pragma unroll
  for (int j = ty; j < 32; j += 8)
    cth[(size_t)(n0 + j) * 512 + c0 + tx] = (_Float16)tile[tx][j];
}

// ---------------------------------------------------------------------------
// Kernel 0c: c_sq[n] = sum_c C[c][n]^2   (fp32, exact inputs)
// ---------------------------------------------------------------------------
__global__ void csq_kernel(const float* __restrict__ c, float* __restrict__ csq) {
  __shared__ float red[256];
  const int t = threadIdx.x;
  const int nl = t & 63;
  const int cs = t >> 6;  // 0..3
  const int n = blockIdx.x * 64 + nl;
  float acc = 0.f;
  for (int cc = cs; cc < 512; cc += 4) {
    float v = c[(size_t)cc * 8192 + n];
    acc = fmaf(v, v, acc);
  }
  red[t] = acc;
  __syncthreads();
  if (t < 64) csq[n] = red[t] + red[t + 64] + red[t + 128] + red[t + 192];
}

__global__ void zero_cnt(unsigned int* c) { *c = 0u; }

// ---------------------------------------------------------------------------
// Kernel 1: single-product f16 GEMM + per-(row, nblock) TOP-2.
//   128x128 tile, BK=64, mfma_f32_16x16x32_f16, 4 waves 2x2, wave tile 64x64.
//   LDS: A 16 KiB + B 16 KiB single buffer, staged via global_load_lds x16.
//   score = c_sq[n] - 2*dot (x_sq constant per row, irrelevant for argmin).
// ---------------------------------------------------------------------------
__launch_bounds__(256, 4)
__global__ void gemm_top2(const _Float16* __restrict__ xh, const _Float16* __restrict__ cth,
                          const float* __restrict__ csq, float* __restrict__ pv1,
                          int* __restrict__ pi1, float* __restrict__ pv2) {
  __shared__ __align__(16) unsigned char smem[32768];
  __shared__ float ep_v1[128][2], ep_v2[128][2];
  __shared__ int ep_i1[128][2];

  const int t = threadIdx.x;
  const int m0 = blockIdx.x * 128;
  const int n0 = blockIdx.y * 128;

  // staging: 1024 chunks (16B = 8 halfs) per operand; chunk = kq*128 + row.
  const _Float16* gA[4];
  const _Float16* gB[4];
#pragma unroll
  for (int p = 0; p < 4; ++p) {
    const int ch = p * 256 + t;
    const int row = ch & 127, kq = ch >> 7;  // kq 0..7 covers K=64
    gA[p] = xh + (size_t)(m0 + row) * 512 + kq * 8;
    gB[p] = cth + (size_t)(n0 + row) * 512 + kq * 8;
  }

  // compute setup
  const int l = t & 63;
  const int w = t >> 6;
  const int wm = w >> 1, wn = w & 1;
  const int l15 = l & 15, lq = l >> 4;
  const int aBase = wm * 64 + l15;         // chunk units, + mf*16
  const int bBase = 1024 + wn * 64 + l15;  // chunk units, + nf*16

  floatx4 acc[4][4] = {};
  const half8* S = (const half8*)smem;

  for (int kc = 0; kc < 8; ++kc) {
    const int k0 = kc * 64;
#pragma unroll
    for (int p = 0; p < 4; ++p) {
      GLL16(gA[p] + k0, smem + (p * 256 + t) * 16);
      GLL16(gB[p] + k0, smem + 16384 + (p * 256 + t) * 16);
    }
    __syncthreads();
#pragma unroll
    for (int ks = 0; ks < 2; ++ks) {
      const int ko = (ks * 4 + lq) * 128;
      half8 a[4], b[4];
#pragma unroll
      for (int f = 0; f < 4; ++f) {
        a[f] = S[ko + aBase + f * 16];
        b[f] = S[ko + bBase + f * 16];
      }
#pragma unroll
      for (int mf = 0; mf < 4; ++mf)
#pragma unroll
        for (int nf = 0; nf < 4; ++nf)
          acc[mf][nf] = __builtin_amdgcn_mfma_f32_16x16x32_f16(a[mf], b[nf], acc[mf][nf], 0, 0, 0);
    }
    __syncthreads();
  }

  // epilogue: top-2 over this block's 128 columns
  float cs[4];
#pragma unroll
  for (int nf = 0; nf < 4; ++nf) cs[nf] = csq[n0 + wn * 64 + nf * 16 + l15];

#pragma unroll
  for (int mf = 0; mf < 4; ++mf) {
#pragma unroll
    for (int reg = 0; reg < 4; ++reg) {
      float v1 = INFINITY, v2 = INFINITY;
      int i1 = 0;
#pragma unroll
      for (int nf = 0; nf < 4; ++nf) {
        float sv = fmaf(-2.f, acc[mf][nf][reg], cs[nf]);
        int si = n0 + wn * 64 + nf * 16 + l15;
        if (sv < v1) { v2 = v1; v1 = sv; i1 = si; }
        else if (sv < v2) { v2 = sv; }
      }
#pragma unroll
      for (int off = 8; off >= 1; off >>= 1) {
        float w1 = __shfl_xor(v1, off, 64);
        int j1 = __shfl_xor(i1, off, 64);
        float w2 = __shfl_xor(v2, off, 64);
        if (w1 < v1 || (w1 == v1 && j1 < i1)) {
          v2 = fminf(v1, w2);
          v1 = w1; i1 = j1;
        } else {
          v2 = fminf(v2, w1);
        }
      }
      if (l15 == 0) {
        int rl = wm * 64 + mf * 16 + lq * 4 + reg;
        ep_v1[rl][wn] = v1;
        ep_i1[rl][wn] = i1;
        ep_v2[rl][wn] = v2;
      }
    }
  }
  __syncthreads();
  if (t < 128) {
    float v1 = ep_v1[t][0], v2 = ep_v2[t][0];
    int i1 = ep_i1[t][0];
    float w1 = ep_v1[t][1], w2 = ep_v2[t][1];
    int j1 = ep_i1[t][1];
    if (w1 < v1 || (w1 == v1 && j1 < i1)) {
      v2 = fminf(v1, w2);
      v1 = w1; i1 = j1;
    } else {
      v2 = fminf(v2, w1);
    }
    const size_t o = (size_t)blockIdx.y * 32768 + m0 + t;
    pv1[o] = v1;
    pi1[o] = i1;
    pv2[o] = v2;
  }
}

// ---------------------------------------------------------------------------
// Kernel 2: merge 64 nblock top-2s; write labels; flag small-margin rows.
// ---------------------------------------------------------------------------
__global__ void final_top2(const float* __restrict__ pv1, const int* __restrict__ pi1,
                           const float* __restrict__ pv2, int* __restrict__ out,
                           unsigned int* __restrict__ cnt, int* __restrict__ list,
                           int* __restrict__ flag) {
  const int row = blockIdx.x * 256 + threadIdx.x;
  float v1 = INFINITY, v2 = INFINITY;
  int i1 = 0;
  for (int nb = 0; nb < 64; ++nb) {
    const size_t o = (size_t)nb * 32768 + row;
    float w1 = pv1[o], w2 = pv2[o];
    int j1 = pi1[o];
    if (w1 < v1 || (w1 == v1 && j1 < i1)) {
      v2 = fminf(v1, w2);
      v1 = w1; i1 = j1;
    } else {
      v2 = fminf(v2, w1);
    }
  }
  out[row] = i1;
  if (v2 - v1 < TAU) {
    unsigned int pos = atomicAdd(cnt, 1u);
    list[pos] = row;
    flag[row] = 1;
  } else {
    flag[row] = 0;
  }
}

// ---------------------------------------------------------------------------
// Kernel 3: accurate fp32 re-argmin for flagged rows.
//   score = csq[k] - 2*dot, dot accumulated in 4 chunks of 128 (|partial|~15,
//   ulp ~1e-6) -> error sigma ~7e-6; final fmaf rounding <=3e-5. Same error
//   class as the round-1 kernel that passed with absmax 0 on ALL rows.
//   Unit = (group of 8 rows) x (1024-wide k slice); fixed grid strides units.
//   Result per (row, slice) -> u64 slot (monotone-key<<32 | k); no atomics.
// ---------------------------------------------------------------------------
__global__ void refine(const float* __restrict__ x, const float* __restrict__ cen,
                       const float* __restrict__ csq, const unsigned int* __restrict__ cnt,
                       const int* __restrict__ list, unsigned long long* __restrict__ slots) {
  __shared__ float xs[8][512];
  __shared__ int rows_s[8];
  __shared__ unsigned long long red2[4][8];
  const int t = threadIdx.x;
  const int lane = t & 63, wid = t >> 6;
  const int n = (int)*cnt;
  const int units = ((n + 7) >> 3) * 8;
  for (int unit = blockIdx.x; unit < units; unit += gridDim.x) {
    const int g = unit >> 3, sl = unit & 7;
    __syncthreads();  // protect xs/rows_s from previous iteration readers
    if (t < 8) {
      int pi = g * 8 + t;
      rows_s[t] = (pi < n) ? list[pi] : -1;
    }
    __syncthreads();
    for (int idx = t; idx < 8 * 512; idx += 256) {
      int p = idx >> 9, c = idx & 511;
      int row = rows_s[p];
      if (row >= 0) {
        int b = row >> 11, s = row & 2047;
        xs[p][c] = x[((size_t)b * 512 + c) * 2048 + s];
      }
    }
    __syncthreads();
    unsigned long long bk[8];
#pragma unroll
    for (int p = 0; p < 8; ++p) bk[p] = ~0ULL;
    for (int i = 0; i < 4; ++i) {
      const int kk = sl * 1024 + i * 256 + t;
      float tot[8] = {};
#pragma unroll
      for (int ch = 0; ch < 4; ++ch) {
        float pa[8] = {};
        for (int c = ch * 128; c < ch * 128 + 128; ++c) {
          float cv = cen[(size_t)c * 8192 + kk];
#pragma unroll
          for (int p = 0; p < 8; ++p) pa[p] = fmaf(xs[p][c], cv, pa[p]);
        }
#pragma unroll
        for (int p = 0; p < 8; ++p) tot[p] += pa[p];
      }
      const float cq = csq[kk];
#pragma unroll
      for (int p = 0; p < 8; ++p) {
        float s = fmaf(-2.f, tot[p], cq);
        unsigned int u = __float_as_uint(s);
        u ^= (unsigned int)(((int)u >> 31)) | 0x80000000u;  // monotone map
        unsigned long long key = ((unsigned long long)u << 32) | (unsigned int)kk;
        if (key < bk[p]) bk[p] = key;
      }
    }
    // wave butterfly u64-min, then cross-wave via tiny LDS
#pragma unroll
    for (int off = 32; off >= 1; off >>= 1) {
#pragma unroll
      for (int p = 0; p < 8; ++p) {
        unsigned long long o = __shfl_xor(bk[p], off, 64);
        if (o < bk[p]) bk[p] = o;
      }
    }
    if (lane == 0) {
#pragma unroll
      for (int p = 0; p < 8; ++p) red2[wid][p] = bk[p];
    }
    __syncthreads();
    if (t < 8) {
      unsigned long long m = red2[0][t];
#pragma unroll
      for (int w2 = 1; w2 < 4; ++w2)
        if (red2[w2][t] < m) m = red2[w2][t];
      int row = rows_s[t];
      if (row >= 0) slots[(size_t)row * 8 + sl] = m;
    }
  }
}

// ---------------------------------------------------------------------------
// Kernel 4: fold refined results into labels.
// ---------------------------------------------------------------------------
__global__ void fixup(const int* __restrict__ flag, const unsigned long long* __restrict__ slots,
                      int* __restrict__ out) {
  const int row = blockIdx.x * 256 + threadIdx.x;
  if (flag[row]) {
    unsigned long long m = ~0ULL;
#pragma unroll
    for (int sl = 0; sl < 8; ++sl) {
      unsigned long long v = slots[(size_t)row * 8 + sl];
      if (v < m) m = v;
    }
    out[row] = (int)(unsigned int)(m & 0xFFFFFFFFULL);
  }
}

// ---------------------------------------------------------------------------
// Fallback (only if ws too small): exact distances, slow but correct.
// ---------------------------------------------------------------------------
__global__ void fallback_kernel(const float* __restrict__ x, const float* __restrict__ cen,
                                int* __restrict__ out) {
  __shared__ float xrow[512];
  __shared__ float rv[256];
  __shared__ int ri[256];
  const int row = blockIdx.x;
  const int b = row >> 11, s = row & 2047;
  const int t = threadIdx.x;
  for (int c = t; c < 512; c += 256) xrow[c] = x[((size_t)b * 512 + c) * 2048 + s];
  __syncthreads();
  float bv = INFINITY;
  int bi = 0;
  for (int k = t; k < 8192; k += 256) {
    float d = 0.f;
    for (int c = 0; c < 512; ++c) {
      float diff = xrow[c] - cen[(size_t)c * 8192 + k];
      d = fmaf(diff, diff, d);
    }
    if (d < bv) { bv = d; bi = k; }
  }
  rv[t] = bv;
  ri[t] = bi;
  __syncthreads();
  for (int off = 128; off > 0; off >>= 1) {
    if (t < off) {
      if (rv[t + off] < rv[t] || (rv[t + off] == rv[t] && ri[t + off] < ri[t])) {
        rv[t] = rv[t + off];
        ri[t] = ri[t + off];
      }
    }
    __syncthreads();
  }
  if (t == 0) out[row] = ri[0];
}

// ---------------------------------------------------------------------------
extern "C" void kernel_launch(void* const* d_in, const int* in_sizes, int n_in,
                              void* d_out, int out_size, void* d_ws, size_t ws_size,
                              hipStream_t stream) {
  const float* x = (const float*)d_in[0];    // [16, 512, 2048]
  const float* cen = (const float*)d_in[1];  // [512, 8192]
  int* out = (int*)d_out;                    // [32768] int32 labels

  const size_t XSZ = (size_t)32768 * 512;  // halfs
  const size_t CSZ = (size_t)8192 * 512;   // halfs
  // layout: xh | cth | csq | pv1 | pv2 | pi1 | slots | flag | list | cnt
  const size_t OFF_CTH = XSZ * 2;
  const size_t OFF_CSQ = OFF_CTH + CSZ * 2;
  const size_t OFF_PV1 = OFF_CSQ + 8192 * 4;
  const size_t OFF_PV2 = OFF_PV1 + (size_t)64 * 32768 * 4;
  const size_t OFF_PI1 = OFF_PV2 + (size_t)64 * 32768 * 4;
  const size_t OFF_SLOT = OFF_PI1 + (size_t)64 * 32768 * 4;
  const size_t OFF_FLAG = OFF_SLOT + (size_t)32768 * 8 * 8;
  const size_t OFF_LIST = OFF_FLAG + (size_t)32768 * 4;
  const size_t OFF_CNT = OFF_LIST + (size_t)32768 * 4;
  const size_t NEED = OFF_CNT + 16;

  if (ws_size < NEED) {
    fallback_kernel<<<32768, 256, 0, stream>>>(x, cen, out);
    return;
  }

  char* ws = (char*)d_ws;
  _Float16* xh = (_Float16*)ws;
  _Float16* cth = (_Float16*)(ws + OFF_CTH);
  float* csq = (float*)(ws + OFF_CSQ);
  float* pv1 = (float*)(ws + OFF_PV1);
  float* pv2 = (float*)(ws + OFF_PV2);
  int* pi1 = (int*)(ws + OFF_PI1);
  unsigned long long* slots = (unsigned long long*)(ws + OFF_SLOT);
  int* flag = (int*)(ws + OFF_FLAG);
  int* list = (int*)(ws + OFF_LIST);
  unsigned int* cnt = (unsigned int*)(ws + OFF_CNT);

  tsplit_x<<<dim3(64, 16, 16), dim3(32, 8), 0, stream>>>(x, xh);
  tsplit_c<<<dim3(256, 16), dim3(32, 8), 0, stream>>>(cen, cth);
  csq_kernel<<<128, 256, 0, stream>>>(cen, csq);
  zero_cnt<<<1, 1, 0, stream>>>(cnt);
  gemm_top2<<<dim3(256, 64), 256, 0, stream>>>(xh, cth, csq, pv1, pi1, pv2);
  final_top2<<<128, 256, 0, stream>>>(pv1, pi1, pv2, out, cnt, list, flag);
  refine<<<512, 256, 0, stream>>>(x, cen, csq, cnt, list, slots);
  fixup<<<128, 256, 0, stream>>>(flag, slots, out);
}

// Round 5
// 806.402 us; speedup vs baseline: 1.7522x; 1.7522x over previous
//
#include <hip/hip_runtime.h>
#include <hip/hip_fp16.h>

typedef _Float16 half8 __attribute__((ext_vector_type(8)));
typedef float floatx4 __attribute__((ext_vector_type(4)));

#define GLL16(g, l)                                                            \
  __builtin_amdgcn_global_load_lds(                                            \
      (const __attribute__((address_space(1))) void*)(g),                      \
      (__attribute__((address_space(3))) void*)(l), 16, 0, 0)

#define TAU 0.25f
#define CMAX 128

__device__ inline unsigned long long score_key(float sc, int k) {
  unsigned int uu = __float_as_uint(sc);
  uu ^= (unsigned int)(((int)uu >> 31)) | 0x80000000u;  // monotone float->u32
  return ((unsigned long long)uu << 32) | (unsigned int)k;
}

// ---------------------------------------------------------------------------
// Kernel 0a: transpose x [b=16, c=512, s=2048] f32 -> xh [row=b*2048+s][c] f16
// ---------------------------------------------------------------------------
__global__ void tsplit_x(const float* __restrict__ x, _Float16* __restrict__ xh) {
  __shared__ float tile[32][33];
  const int s0 = blockIdx.x * 32;
  const int c0 = blockIdx.y * 32;
  const int b = blockIdx.z;
  const int tx = threadIdx.x, ty = threadIdx.y;
  const float* src = x + ((size_t)b * 512 + c0) * 2048 + s0;
#pragma unroll
  for (int i = ty; i < 32; i += 8) tile[i][tx] = src[(size_t)i * 2048 + tx];
  __syncthreads();
#pragma unroll
  for (int j = ty; j < 32; j += 8) {
    const int row = b * 2048 + s0 + j;
    xh[(size_t)row * 512 + c0 + tx] = (_Float16)tile[tx][j];
  }
}

// ---------------------------------------------------------------------------
// Kernel 0b: transpose centroids [c=512, n=8192] f32 -> cth [n][c] f16
// ---------------------------------------------------------------------------
__global__ void tsplit_c(const float* __restrict__ c, _Float16* __restrict__ cth) {
  __shared__ float tile[32][33];
  const int n0 = blockIdx.x * 32;
  const int c0 = blockIdx.y * 32;
  const int tx = threadIdx.x, ty = threadIdx.y;
#pragma unroll
  for (int i = ty; i < 32; i += 8) tile[i][tx] = c[(size_t)(c0 + i) * 8192 + n0 + tx];
  __syncthreads();
#pragma unroll
  for (int j = ty; j < 32; j += 8)
    cth[(size_t)(n0 + j) * 512 + c0 + tx] = (_Float16)tile[tx][j];
}

// ---------------------------------------------------------------------------
// Kernel 0c: c_sq[n] = sum_c C[c][n]^2   (fp32, exact inputs)
// ---------------------------------------------------------------------------
__global__ void csq_kernel(const float* __restrict__ c, float* __restrict__ csq) {
  __shared__ float red[256];
  const int t = threadIdx.x;
  const int nl = t & 63;
  const int cs = t >> 6;  // 0..3
  const int n = blockIdx.x * 64 + nl;
  float acc = 0.f;
  for (int cc = cs; cc < 512; cc += 4) {
    float v = c[(size_t)cc * 8192 + n];
    acc = fmaf(v, v, acc);
  }
  red[t] = acc;
  __syncthreads();
  if (t < 64) csq[n] = red[t] + red[t + 64] + red[t + 128] + red[t + 192];
}

__global__ void zero_cnts(unsigned int* c) { c[threadIdx.x] = 0u; }  // cnt, cnt2

// ---------------------------------------------------------------------------
// Kernel 1: single-product f16 GEMM + per-(row, nblock) TOP-2 (value+index).
//   128x128 tile, BK=64, mfma_f32_16x16x32_f16, 4 waves 2x2, wave tile 64x64.
// ---------------------------------------------------------------------------
__launch_bounds__(256, 4)
__global__ void gemm_top2(const _Float16* __restrict__ xh, const _Float16* __restrict__ cth,
                          const float* __restrict__ csq, float* __restrict__ pv1,
                          int* __restrict__ pi1, float* __restrict__ pv2,
                          int* __restrict__ pi2) {
  __shared__ __align__(16) unsigned char smem[32768];
  __shared__ float ep_v1[128][2], ep_v2[128][2];
  __shared__ int ep_i1[128][2], ep_i2[128][2];

  const int t = threadIdx.x;
  const int m0 = blockIdx.x * 128;
  const int n0 = blockIdx.y * 128;

  const _Float16* gA[4];
  const _Float16* gB[4];
#pragma unroll
  for (int p = 0; p < 4; ++p) {
    const int ch = p * 256 + t;
    const int row = ch & 127, kq = ch >> 7;
    gA[p] = xh + (size_t)(m0 + row) * 512 + kq * 8;
    gB[p] = cth + (size_t)(n0 + row) * 512 + kq * 8;
  }

  const int l = t & 63;
  const int w = t >> 6;
  const int wm = w >> 1, wn = w & 1;
  const int l15 = l & 15, lq = l >> 4;
  const int aBase = wm * 64 + l15;
  const int bBase = 1024 + wn * 64 + l15;

  floatx4 acc[4][4] = {};
  const half8* S = (const half8*)smem;

  for (int kc = 0; kc < 8; ++kc) {
    const int k0 = kc * 64;
#pragma unroll
    for (int p = 0; p < 4; ++p) {
      GLL16(gA[p] + k0, smem + (p * 256 + t) * 16);
      GLL16(gB[p] + k0, smem + 16384 + (p * 256 + t) * 16);
    }
    __syncthreads();
#pragma unroll
    for (int ks = 0; ks < 2; ++ks) {
      const int ko = (ks * 4 + lq) * 128;
      half8 a[4], b[4];
#pragma unroll
      for (int f = 0; f < 4; ++f) {
        a[f] = S[ko + aBase + f * 16];
        b[f] = S[ko + bBase + f * 16];
      }
#pragma unroll
      for (int mf = 0; mf < 4; ++mf)
#pragma unroll
        for (int nf = 0; nf < 4; ++nf)
          acc[mf][nf] = __builtin_amdgcn_mfma_f32_16x16x32_f16(a[mf], b[nf], acc[mf][nf], 0, 0, 0);
    }
    __syncthreads();
  }

  // epilogue: top-2 (value,index) over this block's 128 columns
  float cs[4];
#pragma unroll
  for (int nf = 0; nf < 4; ++nf) cs[nf] = csq[n0 + wn * 64 + nf * 16 + l15];

#pragma unroll
  for (int mf = 0; mf < 4; ++mf) {
#pragma unroll
    for (int reg = 0; reg < 4; ++reg) {
      float v1 = INFINITY, v2 = INFINITY;
      int i1 = 0, i2 = 0;
#pragma unroll
      for (int nf = 0; nf < 4; ++nf) {
        float sv = fmaf(-2.f, acc[mf][nf][reg], cs[nf]);
        int si = n0 + wn * 64 + nf * 16 + l15;
        if (sv < v1) { v2 = v1; i2 = i1; v1 = sv; i1 = si; }
        else if (sv < v2) { v2 = sv; i2 = si; }
      }
#pragma unroll
      for (int off = 8; off >= 1; off >>= 1) {
        float w1 = __shfl_xor(v1, off, 64);
        int j1 = __shfl_xor(i1, off, 64);
        float w2 = __shfl_xor(v2, off, 64);
        int j2 = __shfl_xor(i2, off, 64);
        if (w1 < v1 || (w1 == v1 && j1 < i1)) {
          if (w2 < v1 || (w2 == v1 && j2 < i1)) { v2 = w2; i2 = j2; }
          else { v2 = v1; i2 = i1; }
          v1 = w1; i1 = j1;
        } else {
          if (w1 < v2 || (w1 == v2 && j1 < i2)) { v2 = w1; i2 = j1; }
        }
      }
      if (l15 == 0) {
        int rl = wm * 64 + mf * 16 + lq * 4 + reg;
        ep_v1[rl][wn] = v1;
        ep_i1[rl][wn] = i1;
        ep_v2[rl][wn] = v2;
        ep_i2[rl][wn] = i2;
      }
    }
  }
  __syncthreads();
  if (t < 128) {
    float v1 = ep_v1[t][0], v2 = ep_v2[t][0];
    int i1 = ep_i1[t][0], i2 = ep_i2[t][0];
    float w1 = ep_v1[t][1], w2 = ep_v2[t][1];
    int j1 = ep_i1[t][1], j2 = ep_i2[t][1];
    if (w1 < v1 || (w1 == v1 && j1 < i1)) {
      if (w2 < v1 || (w2 == v1 && j2 < i1)) { v2 = w2; i2 = j2; }
      else { v2 = v1; i2 = i1; }
      v1 = w1; i1 = j1;
    } else {
      if (w1 < v2 || (w1 == v2 && j1 < i2)) { v2 = w1; i2 = j1; }
    }
    const size_t o = (size_t)blockIdx.y * 32768 + m0 + t;
    pv1[o] = v1;
    pi1[o] = i1;
    pv2[o] = v2;
    pi2[o] = i2;
  }
}

// ---------------------------------------------------------------------------
// Kernel 2: merge 64 nblock top-2s; write labels + rowbest; flag small margins.
// ---------------------------------------------------------------------------
__global__ void final_top2(const float* __restrict__ pv1, const int* __restrict__ pi1,
                           const float* __restrict__ pv2, int* __restrict__ out,
                           float* __restrict__ rowbest, unsigned int* __restrict__ cnt,
                           int* __restrict__ list) {
  const int row = blockIdx.x * 256 + threadIdx.x;
  float v1 = INFINITY, v2 = INFINITY;
  int i1 = 0;
  for (int nb = 0; nb < 64; ++nb) {
    const size_t o = (size_t)nb * 32768 + row;
    float w1 = pv1[o], w2 = pv2[o];
    int j1 = pi1[o];
    if (w1 < v1 || (w1 == v1 && j1 < i1)) {
      v2 = fminf(v1, w2);
      v1 = w1; i1 = j1;
    } else {
      v2 = fminf(v2, w1);
    }
  }
  out[row] = i1;
  rowbest[row] = v1;
  if (v2 - v1 < TAU) {
    unsigned int pos = atomicAdd(cnt, 1u);
    list[pos] = row;
  }
}

// ---------------------------------------------------------------------------
// Kernel 3: candidate-set exact rescore for flagged rows.
//   Candidates = per-nblock top-2 entries with approx score < v1g + TAU
//   (true winner must satisfy approx < v1g + 2*delta ~ v1g+0.11 < thr).
//   If any nblock's v2 < thr, a hidden 3rd candidate is possible -> full scan.
//   Exact score: dot in 2 chunks/lane + 64-lane tree sum (err ~1e-5, the
//   error class that passed absmax 0 in rounds 1/4).
// ---------------------------------------------------------------------------
__global__ void cand_refine(const float* __restrict__ x, const float* __restrict__ cen,
                            const float* __restrict__ csq, const float* __restrict__ pv1,
                            const int* __restrict__ pi1, const float* __restrict__ pv2,
                            const int* __restrict__ pi2, const float* __restrict__ rowbest,
                            const unsigned int* __restrict__ cnt, const int* __restrict__ list,
                            unsigned int* __restrict__ cnt2, int* __restrict__ list2,
                            unsigned long long* __restrict__ slots, int* __restrict__ out) {
  __shared__ float xs[512];
  __shared__ int cand[CMAX];
  __shared__ int ccnt_s, needfull_s;
  __shared__ unsigned long long wbest[4];
  const int t = threadIdx.x;
  const int lane = t & 63, wid = t >> 6;
  const int n = (int)*cnt;
  for (int u = blockIdx.x; u < n; u += gridDim.x) {
    __syncthreads();  // protect previous iteration's xs/cand readers
    const int row = list[u];
    const int b = row >> 11, s = row & 2047;
    if (t == 0) { ccnt_s = 0; needfull_s = 0; }
    __syncthreads();
    xs[t] = x[((size_t)(b * 512 + t)) * 2048 + s];
    xs[t + 256] = x[((size_t)(b * 512 + t + 256)) * 2048 + s];
    const float thr = rowbest[row] + TAU;
    if (t < 64) {
      const size_t o = (size_t)t * 32768 + row;
      float w1 = pv1[o];
      if (w1 < thr) {
        int p = atomicAdd(&ccnt_s, 1);
        if (p < CMAX) cand[p] = pi1[o];
        float w2 = pv2[o];
        if (w2 < thr) {
          int q = atomicAdd(&ccnt_s, 1);
          if (q < CMAX) cand[q] = pi2[o];
          needfull_s = 1;  // 3rd-best in this nblock unknown
        }
      }
    }
    __syncthreads();
    int ccnt = ccnt_s < CMAX ? ccnt_s : CMAX;
    unsigned long long best = ~0ULL;
    for (int ci = wid; ci < ccnt; ci += 4) {
      const int k = cand[ci];
      float p0 = 0.f, p1 = 0.f;
#pragma unroll
      for (int j = 0; j < 4; ++j)
        p0 = fmaf(xs[lane + 64 * j], cen[(size_t)(lane + 64 * j) * 8192 + k], p0);
#pragma unroll
      for (int j = 4; j < 8; ++j)
        p1 = fmaf(xs[lane + 64 * j], cen[(size_t)(lane + 64 * j) * 8192 + k], p1);
      float d = p0 + p1;
#pragma unroll
      for (int off = 32; off >= 1; off >>= 1) d += __shfl_xor(d, off, 64);
      unsigned long long key = score_key(fmaf(-2.f, d, csq[k]), k);
      if (key < best) best = key;
    }
    if (lane == 0) wbest[wid] = best;
    __syncthreads();
    if (t == 0) {
      unsigned long long m = wbest[0];
#pragma unroll
      for (int w2 = 1; w2 < 4; ++w2)
        if (wbest[w2] < m) m = wbest[w2];
      out[row] = (int)(unsigned int)(m & 0xFFFFFFFFULL);
      if (needfull_s) {
        slots[row] = ~0ULL;
        unsigned int pos = atomicAdd(cnt2, 1u);
        list2[pos] = row;
      }
    }
  }
}

// ---------------------------------------------------------------------------
// Kernel 4: full 8192-scan for the rare rows needing it (unit = row x 512-k
// slice, 16 units/row, parallel). Exact dot-form, 4-chunk accumulation.
// ---------------------------------------------------------------------------
__global__ void fullscan(const float* __restrict__ x, const float* __restrict__ cen,
                         const float* __restrict__ csq, const unsigned int* __restrict__ cnt2,
                         const int* __restrict__ list2, unsigned long long* __restrict__ slots) {
  __shared__ float xs[512];
  __shared__ unsigned long long red[256];
  const int t = threadIdx.x;
  const int n2 = (int)*cnt2;
  const int units = n2 * 16;
  for (int u = blockIdx.x; u < units; u += gridDim.x) {
    __syncthreads();
    const int row = list2[u >> 4];
    const int sl = u & 15;
    const int b = row >> 11, s = row & 2047;
    xs[t] = x[((size_t)(b * 512 + t)) * 2048 + s];
    xs[t + 256] = x[((size_t)(b * 512 + t + 256)) * 2048 + s];
    __syncthreads();
    const int k0 = sl * 512 + t;
    float tot0 = 0.f, tot1 = 0.f;
#pragma unroll
    for (int ch = 0; ch < 4; ++ch) {
      float a0 = 0.f, a1 = 0.f;
      for (int c = ch * 128; c < ch * 128 + 128; ++c) {
        float xv = xs[c];
        a0 = fmaf(xv, cen[(size_t)c * 8192 + k0], a0);
        a1 = fmaf(xv, cen[(size_t)c * 8192 + k0 + 256], a1);
      }
      tot0 += a0;
      tot1 += a1;
    }
    unsigned long long k1 = score_key(fmaf(-2.f, tot0, csq[k0]), k0);
    unsigned long long k2 = score_key(fmaf(-2.f, tot1, csq[k0 + 256]), k0 + 256);
    red[t] = k1 < k2 ? k1 : k2;
    __syncthreads();
    for (int off = 128; off >= 1; off >>= 1) {
      if (t < off && red[t + off] < red[t]) red[t] = red[t + off];
      __syncthreads();
    }
    if (t == 0) atomicMin(&slots[row], red[0]);
  }
}

// ---------------------------------------------------------------------------
// Kernel 5: fold fullscan results into labels.
// ---------------------------------------------------------------------------
__global__ void fixup2(const unsigned int* __restrict__ cnt2, const int* __restrict__ list2,
                       const unsigned long long* __restrict__ slots, int* __restrict__ out) {
  const int n2 = (int)*cnt2;
  for (int i = blockIdx.x * blockDim.x + threadIdx.x; i < n2; i += blockDim.x * gridDim.x) {
    const int row = list2[i];
    out[row] = (int)(unsigned int)(slots[row] & 0xFFFFFFFFULL);
  }
}

// ---------------------------------------------------------------------------
// Fallback (only if ws too small): exact distances, slow but correct.
// ---------------------------------------------------------------------------
__global__ void fallback_kernel(const float* __restrict__ x, const float* __restrict__ cen,
                                int* __restrict__ out) {
  __shared__ float xrow[512];
  __shared__ float rv[256];
  __shared__ int ri[256];
  const int row = blockIdx.x;
  const int b = row >> 11, s = row & 2047;
  const int t = threadIdx.x;
  for (int c = t; c < 512; c += 256) xrow[c] = x[((size_t)b * 512 + c) * 2048 + s];
  __syncthreads();
  float bv = INFINITY;
  int bi = 0;
  for (int k = t; k < 8192; k += 256) {
    float d = 0.f;
    for (int c = 0; c < 512; ++c) {
      float diff = xrow[c] - cen[(size_t)c * 8192 + k];
      d = fmaf(diff, diff, d);
    }
    if (d < bv) { bv = d; bi = k; }
  }
  rv[t] = bv;
  ri[t] = bi;
  __syncthreads();
  for (int off = 128; off > 0; off >>= 1) {
    if (t < off) {
      if (rv[t + off] < rv[t] || (rv[t + off] == rv[t] && ri[t + off] < ri[t])) {
        rv[t] = rv[t + off];
        ri[t] = ri[t + off];
      }
    }
    __syncthreads();
  }
  if (t == 0) out[row] = ri[0];
}

// ---------------------------------------------------------------------------
extern "C" void kernel_launch(void* const* d_in, const int* in_sizes, int n_in,
                              void* d_out, int out_size, void* d_ws, size_t ws_size,
                              hipStream_t stream) {
  const float* x = (const float*)d_in[0];    // [16, 512, 2048]
  const float* cen = (const float*)d_in[1];  // [512, 8192]
  int* out = (int*)d_out;                    // [32768] int32 labels

  const size_t XSZ = (size_t)32768 * 512;  // halfs
  const size_t CSZ = (size_t)8192 * 512;   // halfs
  const size_t OFF_CTH = XSZ * 2;
  const size_t OFF_CSQ = OFF_CTH + CSZ * 2;
  const size_t OFF_PV1 = OFF_CSQ + 8192 * 4;
  const size_t OFF_PV2 = OFF_PV1 + (size_t)64 * 32768 * 4;
  const size_t OFF_PI1 = OFF_PV2 + (size_t)64 * 32768 * 4;
  const size_t OFF_PI2 = OFF_PI1 + (size_t)64 * 32768 * 4;
  const size_t OFF_RB = OFF_PI2 + (size_t)64 * 32768 * 4;
  const size_t OFF_SLOT = OFF_RB + (size_t)32768 * 4;
  const size_t OFF_LIST = OFF_SLOT + (size_t)32768 * 8;
  const size_t OFF_LIST2 = OFF_LIST + (size_t)32768 * 4;
  const size_t OFF_CNT = OFF_LIST2 + (size_t)32768 * 4;
  const size_t NEED = OFF_CNT + 16;

  if (ws_size < NEED) {
    fallback_kernel<<<32768, 256, 0, stream>>>(x, cen, out);
    return;
  }

  char* ws = (char*)d_ws;
  _Float16* xh = (_Float16*)ws;
  _Float16* cth = (_Float16*)(ws + OFF_CTH);
  float* csq = (float*)(ws + OFF_CSQ);
  float* pv1 = (float*)(ws + OFF_PV1);
  float* pv2 = (float*)(ws + OFF_PV2);
  int* pi1 = (int*)(ws + OFF_PI1);
  int* pi2 = (int*)(ws + OFF_PI2);
  float* rowbest = (float*)(ws + OFF_RB);
  unsigned long long* slots = (unsigned long long*)(ws + OFF_SLOT);
  int* list = (int*)(ws + OFF_LIST);
  int* list2 = (int*)(ws + OFF_LIST2);
  unsigned int* cnts = (unsigned int*)(ws + OFF_CNT);  // [0]=cnt, [1]=cnt2

  tsplit_x<<<dim3(64, 16, 16), dim3(32, 8), 0, stream>>>(x, xh);
  tsplit_c<<<dim3(256, 16), dim3(32, 8), 0, stream>>>(cen, cth);
  csq_kernel<<<128, 256, 0, stream>>>(cen, csq);
  zero_cnts<<<1, 2, 0, stream>>>(cnts);
  gemm_top2<<<dim3(256, 64), 256, 0, stream>>>(xh, cth, csq, pv1, pi1, pv2, pi2);
  final_top2<<<128, 256, 0, stream>>>(pv1, pi1, pv2, out, rowbest, cnts, list);
  cand_refine<<<512, 256, 0, stream>>>(x, cen, csq, pv1, pi1, pv2, pi2, rowbest,
                                       cnts, list, cnts + 1, list2, slots, out);
  fullscan<<<256, 256, 0, stream>>>(x, cen, csq, cnts + 1, list2, slots);
  fixup2<<<4, 256, 0, stream>>>(cnts + 1, list2, slots, out);
}